// Round 2
// baseline (152.946 us; speedup 1.0000x reference)
//
#include <hip/hip_runtime.h>

typedef __bf16 bf16x8 __attribute__((ext_vector_type(8)));
typedef float f32x4 __attribute__((ext_vector_type(4)));
typedef unsigned int u32x4 __attribute__((ext_vector_type(4)));

__device__ __forceinline__ unsigned short f2bf(float f) {
  unsigned u = __builtin_bit_cast(unsigned, f);
  u += 0x7FFFu + ((u >> 16) & 1u);
  return (unsigned short)(u >> 16);
}

__device__ __forceinline__ u32x4 pack8(f32x4 a, f32x4 b) {
  u32x4 pk;
  pk[0] = (unsigned)f2bf(a[0]) | ((unsigned)f2bf(a[1]) << 16);
  pk[1] = (unsigned)f2bf(a[2]) | ((unsigned)f2bf(a[3]) << 16);
  pk[2] = (unsigned)f2bf(b[0]) | ((unsigned)f2bf(b[1]) << 16);
  pk[3] = (unsigned)f2bf(b[2]) | ((unsigned)f2bf(b[3]) << 16);
  return pk;
}
__device__ __forceinline__ bf16x8 cvt8(f32x4 a, f32x4 b) {
  return __builtin_bit_cast(bf16x8, pack8(a, b));
}

// ---------------- W transpose: W[512 f][512 d] f32 -> Wt[512 d][512 f] bf16 --------
__global__ void transpose_cvt(const float* __restrict__ in, unsigned short* __restrict__ out) {
  __shared__ float tile[32][33];
  const int r0 = blockIdx.x * 32, c0 = blockIdx.y * 32;
  const int tx = threadIdx.x, ty = threadIdx.y;
#pragma unroll
  for (int i = 0; i < 4; ++i) tile[ty + i * 8][tx] = in[(size_t)(r0 + ty + i * 8) * 512 + c0 + tx];
  __syncthreads();
#pragma unroll
  for (int i = 0; i < 4; ++i) {
    const int cc = ty + i * 8;
    out[(size_t)(c0 + cc) * 512 + r0 + tx] = f2bf(tile[tx][cc]);
  }
}

// ---------------- gemm_y: yT = (x @ W)^T  (bf16) + exact row mask ------------------
// M = B*N = 16384 flat, K = 512, N = 512. No LDS, no barriers. A = x fp32 direct
// (in-reg convert), B = Wt bf16 direct (L2-resident). Epilogue writes yT[b][d][n].
__global__ __launch_bounds__(512, 2) void gemm_y(const float* __restrict__ x,
                                                 const unsigned short* __restrict__ wT,
                                                 unsigned short* __restrict__ yT,
                                                 int* __restrict__ mask) {
  const int m0 = blockIdx.x * 64;
  const int b = m0 >> 11, n0 = m0 & 2047;
  const int tid = threadIdx.x, lane = tid & 63, w = tid >> 6;
  const int r = lane & 15, hi = lane >> 4;

  const float* xp[4];
  const unsigned short* bp[4];
#pragma unroll
  for (int mi = 0; mi < 4; ++mi) xp[mi] = x + (size_t)(m0 + mi * 16 + r) * 512 + hi * 8;
#pragma unroll
  for (int ni = 0; ni < 4; ++ni) bp[ni] = wT + (size_t)(w * 64 + ni * 16 + r) * 512 + hi * 8;

  f32x4 acc[4][4] = {};
  unsigned anz[4] = {0u, 0u, 0u, 0u};

#pragma unroll 1
  for (int t = 0; t < 8; ++t) {
    bf16x8 ac[4][2], bc[4][2];
#pragma unroll
    for (int mi = 0; mi < 4; ++mi)
#pragma unroll
      for (int kk = 0; kk < 2; ++kk) {
        f32x4 p0 = *(const f32x4*)(xp[mi] + t * 64 + kk * 32);
        f32x4 p1 = *(const f32x4*)(xp[mi] + t * 64 + kk * 32 + 4);
        if (w == 0) {
          u32x4 u0 = __builtin_bit_cast(u32x4, p0), u1 = __builtin_bit_cast(u32x4, p1);
          anz[mi] |= (u0[0] | u0[1] | u0[2] | u0[3] | u1[0] | u1[1] | u1[2] | u1[3]) & 0x7fffffffu;
        }
        ac[mi][kk] = cvt8(p0, p1);
      }
#pragma unroll
    for (int ni = 0; ni < 4; ++ni)
#pragma unroll
      for (int kk = 0; kk < 2; ++kk) bc[ni][kk] = *(const bf16x8*)(bp[ni] + t * 64 + kk * 32);
#pragma unroll
    for (int kk = 0; kk < 2; ++kk)
#pragma unroll
      for (int mi = 0; mi < 4; ++mi)
#pragma unroll
        for (int ni = 0; ni < 4; ++ni)
          acc[mi][ni] = __builtin_amdgcn_mfma_f32_16x16x32_bf16(ac[mi][kk], bc[ni][kk],
                                                                acc[mi][ni], 0, 0, 0);
  }

  // exact row mask: row all-zero iff OR of |bits| over the row == 0
  if (w == 0) {
#pragma unroll
    for (int mi = 0; mi < 4; ++mi) {
      unsigned v = anz[mi];
      v |= __shfl_xor(v, 16);
      v |= __shfl_xor(v, 32);
      if (hi == 0) mask[b * 2048 + n0 + mi * 16 + r] = (v != 0u) ? 1 : 0;
    }
  }

  // yT[b][d][n] write: rr runs along n -> contiguous 8B stores
#pragma unroll
  for (int mi = 0; mi < 4; ++mi)
#pragma unroll
    for (int ni = 0; ni < 4; ++ni) {
      const int col = w * 64 + ni * 16 + r;
      ushort4 s;
      s.x = f2bf(acc[mi][ni][0]);
      s.y = f2bf(acc[mi][ni][1]);
      s.z = f2bf(acc[mi][ni][2]);
      s.w = f2bf(acc[mi][ni][3]);
      *(ushort4*)(yT + (((size_t)b * 512 + col) << 11) + n0 + mi * 16 + hi * 4) = s;
    }
}

// ---------------- gemm_big: out = relu(a @ y) * mask -------------------------------
// Per batch: M=2048, K=2048 (n), N=512 (d). Block tile 64x512, 8 waves (64x64 each),
// BK=64. A (fp32) reg-staged -> bf16 LDS (dbuf, XOR-swizzled), ~1.9-iter-deep
// prefetch. B frags direct from yT (bf16, 2MB/batch, XCD-pinned L2), reg-dbuf with
// even/odd static buffers (no copies). Raw s_barrier + lgkmcnt(0) fence only:
// global loads stay in flight across the barrier (counted-vmcnt left to compiler).
__global__ __launch_bounds__(512, 2) void gemm_big(const float* __restrict__ a,
                                                   const unsigned short* __restrict__ yT,
                                                   const int* __restrict__ mask,
                                                   float* __restrict__ out) {
  __shared__ __align__(16) char Abuf[2][64 * 128];  // 64 rows x 64 k x bf16 = 8KB each
  const int bid = blockIdx.x;
  const int b = bid & 7, mt = bid >> 3;  // bid%8 = batch -> XCD pinning for yT[b]
  const int m0 = mt * 64;
  const float* ab = a + ((size_t)b * 2048 + m0) * 2048;
  const unsigned short* yb = yT + (size_t)b * 512 * 2048;

  const int tid = threadIdx.x, lane = tid & 63, w = tid >> 6;
  const int r = lane & 15, hi = lane >> 4;

  // A staging: thread loads 8 consecutive fp32 of one row of the 64x64 tile
  const int arow = tid >> 3, acol = (tid & 7) * 8;
  const float* ap = ab + (size_t)arow * 2048 + acol;
  const int awoff = (arow * 128 + acol * 2) ^ ((arow & 7) << 4);

  int aoff[4][2];
#pragma unroll
  for (int mi = 0; mi < 4; ++mi)
#pragma unroll
    for (int kk = 0; kk < 2; ++kk)
      aoff[mi][kk] = (((mi * 16 + r) * 128) + kk * 64 + hi * 16) ^ ((r & 7) << 4);

  const unsigned short* bp[4];
#pragma unroll
  for (int ni = 0; ni < 4; ++ni) bp[ni] = yb + (size_t)(w * 64 + ni * 16 + r) * 2048 + hi * 8;

  f32x4 acc[4][4] = {};
  f32x4 g0a, g0b, g1a, g1b;
  bf16x8 bc0[4][2], bc1[4][2];

  // prologue: A tiles 0,1 in flight; B tile 0; stage A tile 0
  g0a = *(const f32x4*)(ap);
  g0b = *(const f32x4*)(ap + 4);
  g1a = *(const f32x4*)(ap + 64);
  g1b = *(const f32x4*)(ap + 68);
#pragma unroll
  for (int ni = 0; ni < 4; ++ni)
#pragma unroll
    for (int kk = 0; kk < 2; ++kk) bc0[ni][kk] = *(const bf16x8*)(bp[ni] + kk * 32);
  *(u32x4*)(&Abuf[0][awoff]) = pack8(g0a, g0b);
  asm volatile("s_waitcnt lgkmcnt(0)" ::: "memory");
  __builtin_amdgcn_s_barrier();

#define BIG_BODY(tt, BUF, BCC, BCN, GIA, GIB, GPA, GPB)                         \
  {                                                                             \
    const int tn1 = (tt) + 1, tn2 = (tt) + 2;                                   \
    if (tn1 < 32) {                                                             \
      _Pragma("unroll") for (int ni = 0; ni < 4; ++ni)                          \
          _Pragma("unroll") for (int kk = 0; kk < 2; ++kk)                      \
              BCN[ni][kk] = *(const bf16x8*)(bp[ni] + tn1 * 64 + kk * 32);      \
    }                                                                           \
    if (tn2 < 32) {                                                             \
      GIA = *(const f32x4*)(ap + tn2 * 64);                                     \
      GIB = *(const f32x4*)(ap + tn2 * 64 + 4);                                 \
    }                                                                           \
    bf16x8 af[4][2];                                                            \
    _Pragma("unroll") for (int mi = 0; mi < 4; ++mi)                            \
        _Pragma("unroll") for (int kk = 0; kk < 2; ++kk)                        \
            af[mi][kk] = *(const bf16x8*)(&Abuf[BUF][aoff[mi][kk]]);            \
    _Pragma("unroll") for (int kk = 0; kk < 2; ++kk)                            \
        _Pragma("unroll") for (int mi = 0; mi < 4; ++mi)                        \
            _Pragma("unroll") for (int ni = 0; ni < 4; ++ni)                    \
                acc[mi][ni] = __builtin_amdgcn_mfma_f32_16x16x32_bf16(          \
                    af[mi][kk], BCC[ni][kk], acc[mi][ni], 0, 0, 0);             \
    if (tn1 < 32) {                                                             \
      *(u32x4*)(&Abuf[(BUF) ^ 1][awoff]) = pack8(GPA, GPB);                     \
      asm volatile("s_waitcnt lgkmcnt(0)" ::: "memory");                        \
      __builtin_amdgcn_s_barrier();                                             \
    }                                                                           \
  }

#pragma unroll 1
  for (int t = 0; t < 32; t += 2) {
    BIG_BODY(t, 0, bc0, bc1, g0a, g0b, g1a, g1b)
    BIG_BODY(t + 1, 1, bc1, bc0, g1a, g1b, g0a, g0b)
  }
#undef BIG_BODY

  // epilogue: relu + row mask + fp32 store (64B-coalesced per 16-lane group)
  const int* mrow = mask + b * 2048 + m0;
#pragma unroll
  for (int mi = 0; mi < 4; ++mi) {
    const int4 mv = *(const int4*)(mrow + mi * 16 + hi * 4);
    const int mvv[4] = {mv.x, mv.y, mv.z, mv.w};
#pragma unroll
    for (int ni = 0; ni < 4; ++ni) {
      const int col = w * 64 + ni * 16 + r;
      float* op = out + ((size_t)(b * 2048 + m0 + mi * 16 + hi * 4)) * 512 + col;
#pragma unroll
      for (int rr = 0; rr < 4; ++rr) {
        float v = fmaxf(acc[mi][ni][rr], 0.0f);
        if (mvv[rr] == 0) v = 0.0f;
        op[(size_t)rr * 512] = v;
      }
    }
  }
}

// ---------------- launch ----------------------------------------------------------
extern "C" void kernel_launch(void* const* d_in, const int* in_sizes, int n_in,
                              void* d_out, int out_size, void* d_ws, size_t ws_size,
                              hipStream_t stream) {
  const float* x = (const float*)d_in[0];   // [8][2048][512]
  const float* a = (const float*)d_in[1];   // [8][2048][2048]
  const float* wk = (const float*)d_in[2];  // [512][512]
  float* out = (float*)d_out;               // [8][2048][512]

  char* ws = (char*)d_ws;
  unsigned short* wT = (unsigned short*)ws;                          // 512 KB
  unsigned short* yT = (unsigned short*)(ws + (1u << 19));           // 16 MB
  int* mask = (int*)(ws + (1u << 19) + (16u << 20));                 // 64 KB

  transpose_cvt<<<dim3(16, 16), dim3(32, 8), 0, stream>>>(wk, wT);
  gemm_y<<<dim3(256), dim3(512), 0, stream>>>(x, wT, yT, mask);
  gemm_big<<<dim3(256), dim3(512), 0, stream>>>(a, yT, mask, out);
}

// Round 3
// 152.809 us; speedup vs baseline: 1.0009x; 1.0009x over previous
//
#include <hip/hip_runtime.h>

typedef __bf16 bf16x8 __attribute__((ext_vector_type(8)));
typedef float f32x4 __attribute__((ext_vector_type(4)));
typedef unsigned int u32x4 __attribute__((ext_vector_type(4)));

__device__ __forceinline__ unsigned short f2bf(float f) {
  unsigned u = __builtin_bit_cast(unsigned, f);
  u += 0x7FFFu + ((u >> 16) & 1u);
  return (unsigned short)(u >> 16);
}

__device__ __forceinline__ u32x4 pack8(f32x4 a, f32x4 b) {
  u32x4 pk;
  pk[0] = (unsigned)f2bf(a[0]) | ((unsigned)f2bf(a[1]) << 16);
  pk[1] = (unsigned)f2bf(a[2]) | ((unsigned)f2bf(a[3]) << 16);
  pk[2] = (unsigned)f2bf(b[0]) | ((unsigned)f2bf(b[1]) << 16);
  pk[3] = (unsigned)f2bf(b[2]) | ((unsigned)f2bf(b[3]) << 16);
  return pk;
}
__device__ __forceinline__ bf16x8 cvt8(f32x4 a, f32x4 b) {
  return __builtin_bit_cast(bf16x8, pack8(a, b));
}

// ---------------- W transpose: W[512 f][512 d] f32 -> Wt[512 d][512 f] bf16 --------
__global__ void transpose_cvt(const float* __restrict__ in, unsigned short* __restrict__ out) {
  __shared__ float tile[32][33];
  const int r0 = blockIdx.x * 32, c0 = blockIdx.y * 32;
  const int tx = threadIdx.x, ty = threadIdx.y;
#pragma unroll
  for (int i = 0; i < 4; ++i) tile[ty + i * 8][tx] = in[(size_t)(r0 + ty + i * 8) * 512 + c0 + tx];
  __syncthreads();
#pragma unroll
  for (int i = 0; i < 4; ++i) {
    const int cc = ty + i * 8;
    out[(size_t)(c0 + cc) * 512 + r0 + tx] = f2bf(tile[tx][cc]);
  }
}

// ---------------- gemm_y: yT = (x @ W)^T  (bf16) + exact row mask ------------------
// M = B*N = 16384 flat, K = 512, N = 512. No LDS, no barriers. A = x fp32 direct
// (in-reg convert), B = Wt bf16 direct (L2-resident). Epilogue writes yT[b][d][n].
// launch_bounds(512,1): 256-VGPR budget so the register pipeline survives regalloc.
__global__ __launch_bounds__(512, 1) void gemm_y(const float* __restrict__ x,
                                                 const unsigned short* __restrict__ wT,
                                                 unsigned short* __restrict__ yT,
                                                 int* __restrict__ mask) {
  const int m0 = blockIdx.x * 64;
  const int b = m0 >> 11, n0 = m0 & 2047;
  const int tid = threadIdx.x, lane = tid & 63, w = tid >> 6;
  const int r = lane & 15, hi = lane >> 4;

  const float* xp[4];
  const unsigned short* bp[4];
#pragma unroll
  for (int mi = 0; mi < 4; ++mi) xp[mi] = x + (size_t)(m0 + mi * 16 + r) * 512 + hi * 8;
#pragma unroll
  for (int ni = 0; ni < 4; ++ni) bp[ni] = wT + (size_t)(w * 64 + ni * 16 + r) * 512 + hi * 8;

  f32x4 acc[4][4] = {};
  unsigned anz[4] = {0u, 0u, 0u, 0u};

#pragma unroll 1
  for (int t = 0; t < 8; ++t) {
    bf16x8 ac[4][2], bc[4][2];
#pragma unroll
    for (int mi = 0; mi < 4; ++mi)
#pragma unroll
      for (int kk = 0; kk < 2; ++kk) {
        f32x4 p0 = *(const f32x4*)(xp[mi] + t * 64 + kk * 32);
        f32x4 p1 = *(const f32x4*)(xp[mi] + t * 64 + kk * 32 + 4);
        if (w == 0) {
          u32x4 u0 = __builtin_bit_cast(u32x4, p0), u1 = __builtin_bit_cast(u32x4, p1);
          anz[mi] |= (u0[0] | u0[1] | u0[2] | u0[3] | u1[0] | u1[1] | u1[2] | u1[3]) & 0x7fffffffu;
        }
        ac[mi][kk] = cvt8(p0, p1);
      }
#pragma unroll
    for (int ni = 0; ni < 4; ++ni)
#pragma unroll
      for (int kk = 0; kk < 2; ++kk) bc[ni][kk] = *(const bf16x8*)(bp[ni] + t * 64 + kk * 32);
#pragma unroll
    for (int kk = 0; kk < 2; ++kk)
#pragma unroll
      for (int mi = 0; mi < 4; ++mi)
#pragma unroll
        for (int ni = 0; ni < 4; ++ni)
          acc[mi][ni] = __builtin_amdgcn_mfma_f32_16x16x32_bf16(ac[mi][kk], bc[ni][kk],
                                                                acc[mi][ni], 0, 0, 0);
  }

  // exact row mask: row all-zero iff OR of |bits| over the row == 0
  if (w == 0) {
#pragma unroll
    for (int mi = 0; mi < 4; ++mi) {
      unsigned v = anz[mi];
      v |= __shfl_xor(v, 16);
      v |= __shfl_xor(v, 32);
      if (hi == 0) mask[b * 2048 + n0 + mi * 16 + r] = (v != 0u) ? 1 : 0;
    }
  }

  // yT[b][d][n] write: rr runs along n -> contiguous 8B stores
#pragma unroll
  for (int mi = 0; mi < 4; ++mi)
#pragma unroll
    for (int ni = 0; ni < 4; ++ni) {
      const int col = w * 64 + ni * 16 + r;
      ushort4 s;
      s.x = f2bf(acc[mi][ni][0]);
      s.y = f2bf(acc[mi][ni][1]);
      s.z = f2bf(acc[mi][ni][2]);
      s.w = f2bf(acc[mi][ni][3]);
      *(ushort4*)(yT + (((size_t)b * 512 + col) << 11) + n0 + mi * 16 + hi * 4) = s;
    }
}

// ---------------- gemm_big: out = relu(a @ y) * mask -------------------------------
// Per batch: M=2048, K=2048 (n), N=512 (d). Block tile 64x512, 8 waves (64x64 each),
// BK=64. A (fp32) reg-staged -> bf16 LDS (dbuf, XOR-swizzled), 2-iter-deep prefetch.
// B frags direct from yT (bf16, 2MB/batch, XCD-pinned L2), reg-dbuf even/odd static
// buffers. Raw s_barrier + lgkmcnt(0) only; globals stay in flight across barrier.
// launch_bounds(512,1): grid=256 is 1 block/CU anyway; give regalloc the full 256
// VGPRs so it does NOT sink the prefetch loads (round-2 failure: VGPR=104 cap).
__global__ __launch_bounds__(512, 1) void gemm_big(const float* __restrict__ a,
                                                   const unsigned short* __restrict__ yT,
                                                   const int* __restrict__ mask,
                                                   float* __restrict__ out) {
  __shared__ __align__(16) char Abuf[2][64 * 128];  // 64 rows x 64 k x bf16 = 8KB each
  const int bid = blockIdx.x;
  const int b = bid & 7, mt = bid >> 3;  // bid%8 = batch -> XCD pinning for yT[b]
  const int m0 = mt * 64;
  const float* ab = a + ((size_t)b * 2048 + m0) * 2048;
  const unsigned short* yb = yT + (size_t)b * 512 * 2048;

  const int tid = threadIdx.x, lane = tid & 63, w = tid >> 6;
  const int r = lane & 15, hi = lane >> 4;

  // A staging: thread loads 8 consecutive fp32 of one row of the 64x64 tile
  const int arow = tid >> 3, acol = (tid & 7) * 8;
  const float* ap = ab + (size_t)arow * 2048 + acol;
  const int awoff = (arow * 128 + acol * 2) ^ ((arow & 7) << 4);

  int aoff[4][2];
#pragma unroll
  for (int mi = 0; mi < 4; ++mi)
#pragma unroll
    for (int kk = 0; kk < 2; ++kk)
      aoff[mi][kk] = (((mi * 16 + r) * 128) + kk * 64 + hi * 16) ^ ((r & 7) << 4);

  const unsigned short* bp[4];
#pragma unroll
  for (int ni = 0; ni < 4; ++ni) bp[ni] = yb + (size_t)(w * 64 + ni * 16 + r) * 2048 + hi * 8;

  f32x4 acc[4][4] = {};
  f32x4 g0a, g0b, g1a, g1b;
  bf16x8 bc0[4][2], bc1[4][2];

  // prologue: A tiles 0,1 in flight; B tile 0; stage A tile 0
  g0a = *(const f32x4*)(ap);
  g0b = *(const f32x4*)(ap + 4);
  g1a = *(const f32x4*)(ap + 64);
  g1b = *(const f32x4*)(ap + 68);
#pragma unroll
  for (int ni = 0; ni < 4; ++ni)
#pragma unroll
    for (int kk = 0; kk < 2; ++kk) bc0[ni][kk] = *(const bf16x8*)(bp[ni] + kk * 32);
  *(u32x4*)(&Abuf[0][awoff]) = pack8(g0a, g0b);
  asm volatile("s_waitcnt lgkmcnt(0)" ::: "memory");
  __builtin_amdgcn_s_barrier();

#define BIG_BODY(tt, BUF, BCC, BCN, GIA, GIB, GPA, GPB)                         \
  {                                                                             \
    const int tn1 = (tt) + 1, tn2 = (tt) + 2;                                   \
    if (tn1 < 32) {                                                             \
      _Pragma("unroll") for (int ni = 0; ni < 4; ++ni)                          \
          _Pragma("unroll") for (int kk = 0; kk < 2; ++kk)                      \
              BCN[ni][kk] = *(const bf16x8*)(bp[ni] + tn1 * 64 + kk * 32);      \
    }                                                                           \
    if (tn2 < 32) {                                                             \
      GIA = *(const f32x4*)(ap + tn2 * 64);                                     \
      GIB = *(const f32x4*)(ap + tn2 * 64 + 4);                                 \
    }                                                                           \
    bf16x8 af[4][2];                                                            \
    _Pragma("unroll") for (int mi = 0; mi < 4; ++mi)                            \
        _Pragma("unroll") for (int kk = 0; kk < 2; ++kk)                        \
            af[mi][kk] = *(const bf16x8*)(&Abuf[BUF][aoff[mi][kk]]);            \
    _Pragma("unroll") for (int kk = 0; kk < 2; ++kk)                            \
        _Pragma("unroll") for (int mi = 0; mi < 4; ++mi)                        \
            _Pragma("unroll") for (int ni = 0; ni < 4; ++ni)                    \
                acc[mi][ni] = __builtin_amdgcn_mfma_f32_16x16x32_bf16(          \
                    af[mi][kk], BCC[ni][kk], acc[mi][ni], 0, 0, 0);             \
    if (tn1 < 32) {                                                             \
      *(u32x4*)(&Abuf[(BUF) ^ 1][awoff]) = pack8(GPA, GPB);                     \
      asm volatile("s_waitcnt lgkmcnt(0)" ::: "memory");                        \
      __builtin_amdgcn_s_barrier();                                             \
    }                                                                           \
  }

#pragma unroll 1
  for (int t = 0; t < 32; t += 2) {
    BIG_BODY(t, 0, bc0, bc1, g0a, g0b, g1a, g1b)
    BIG_BODY(t + 1, 1, bc1, bc0, g1a, g1b, g0a, g0b)
  }
#undef BIG_BODY

  // epilogue: relu + row mask + fp32 store (64B-coalesced per 16-lane group)
  const int* mrow = mask + b * 2048 + m0;
#pragma unroll
  for (int mi = 0; mi < 4; ++mi) {
    const int4 mv = *(const int4*)(mrow + mi * 16 + hi * 4);
    const int mvv[4] = {mv.x, mv.y, mv.z, mv.w};
#pragma unroll
    for (int ni = 0; ni < 4; ++ni) {
      const int col = w * 64 + ni * 16 + r;
      float* op = out + ((size_t)(b * 2048 + m0 + mi * 16 + hi * 4)) * 512 + col;
#pragma unroll
      for (int rr = 0; rr < 4; ++rr) {
        float v = fmaxf(acc[mi][ni][rr], 0.0f);
        if (mvv[rr] == 0) v = 0.0f;
        op[(size_t)rr * 512] = v;
      }
    }
  }
}

// ---------------- launch ----------------------------------------------------------
extern "C" void kernel_launch(void* const* d_in, const int* in_sizes, int n_in,
                              void* d_out, int out_size, void* d_ws, size_t ws_size,
                              hipStream_t stream) {
  const float* x = (const float*)d_in[0];   // [8][2048][512]
  const float* a = (const float*)d_in[1];   // [8][2048][2048]
  const float* wk = (const float*)d_in[2];  // [512][512]
  float* out = (float*)d_out;               // [8][2048][512]

  char* ws = (char*)d_ws;
  unsigned short* wT = (unsigned short*)ws;                          // 512 KB
  unsigned short* yT = (unsigned short*)(ws + (1u << 19));           // 16 MB
  int* mask = (int*)(ws + (1u << 19) + (16u << 20));                 // 64 KB

  transpose_cvt<<<dim3(16, 16), dim3(32, 8), 0, stream>>>(wk, wT);
  gemm_y<<<dim3(256), dim3(512), 0, stream>>>(x, wT, yT, mask);
  gemm_big<<<dim3(256), dim3(512), 0, stream>>>(a, yT, mask, out);
}

// Round 4
// 113.254 us; speedup vs baseline: 1.3505x; 1.3493x over previous
//
#include <hip/hip_runtime.h>

typedef __bf16 bf16x8 __attribute__((ext_vector_type(8)));
typedef float f32x4 __attribute__((ext_vector_type(4)));
typedef unsigned int u32x4 __attribute__((ext_vector_type(4)));

__device__ __forceinline__ unsigned short f2bf(float f) {
  unsigned u = __builtin_bit_cast(unsigned, f);
  u += 0x7FFFu + ((u >> 16) & 1u);
  return (unsigned short)(u >> 16);
}

// async global->LDS, 16B per lane. LDS dest = wave-uniform base + lane*16 (HW rule).
__device__ __forceinline__ void gl2lds16(const void* g, void* l) {
  __builtin_amdgcn_global_load_lds((const __attribute__((address_space(1))) void*)g,
                                   (__attribute__((address_space(3))) void*)l, 16, 0, 0);
}

// opaque (un-sinkable) 16B global load
__device__ __forceinline__ bf16x8 gload16(const void* p) {
  bf16x8 r;
  asm volatile("global_load_dwordx4 %0, %1, off" : "=v"(r) : "v"(p));
  return r;
}

__device__ __forceinline__ bf16x8 cvt8v(f32x4 a, f32x4 b) {
  bf16x8 r;
  r[0] = (__bf16)a[0]; r[1] = (__bf16)a[1]; r[2] = (__bf16)a[2]; r[3] = (__bf16)a[3];
  r[4] = (__bf16)b[0]; r[5] = (__bf16)b[1]; r[6] = (__bf16)b[2]; r[7] = (__bf16)b[3];
  return r;
}

// ---------------- W transpose: W[512 f][512 d] f32 -> Wt[512 d][512 f] bf16 --------
__global__ void transpose_cvt(const float* __restrict__ in, unsigned short* __restrict__ out) {
  __shared__ float tile[32][33];
  const int r0 = blockIdx.x * 32, c0 = blockIdx.y * 32;
  const int tx = threadIdx.x, ty = threadIdx.y;
#pragma unroll
  for (int i = 0; i < 4; ++i) tile[ty + i * 8][tx] = in[(size_t)(r0 + ty + i * 8) * 512 + c0 + tx];
  __syncthreads();
#pragma unroll
  for (int i = 0; i < 4; ++i) {
    const int cc = ty + i * 8;
    out[(size_t)(c0 + cc) * 512 + r0 + tx] = f2bf(tile[tx][cc]);
  }
}

// ---------------- unified pipelined GEMM -------------------------------------------
// Block: 64 M-rows x full N (=512), 8 waves (wave tile 64x64), BK=64, NT K-steps.
// A fp32 -> LDS ring[4] via global_load_lds (pre-swizzled source, chunk16 ^= row&7);
// B bf16 direct-from-global via asm loads, reg double-buffered 1 iter ahead.
// Per iter: vmcnt(2) -> sched_barrier -> s_barrier -> B(t+1) -> A(t+3) -> compute.
// vmcnt counting: per iter exactly 8 B-asm + 2 glds issued, order pinned by
// sched_barrier(0); tail issues clamped (redundant loads) to keep count uniform.
template <int APITCH, int BPITCH, int NT, bool IS_Y>
__global__ __launch_bounds__(512, 1) void gemm_pipe(const float* __restrict__ A0,
                                                    const unsigned short* __restrict__ B0,
                                                    unsigned short* __restrict__ yT,
                                                    int* __restrict__ mask,
                                                    float* __restrict__ out) {
  __shared__ __align__(16) float Abuf[4][64 * 64];  // 64 KB ring

  const int bid = blockIdx.x;
  int b, m0loc;
  const float* Ab;
  const unsigned short* Bb;
  if constexpr (IS_Y) {
    b = bid >> 5;                 // 32 blocks per batch (M flat = 16384)
    m0loc = (bid & 31) * 64;
    Ab = A0 + (size_t)bid * 64 * APITCH;
    Bb = B0;                      // wT shared
  } else {
    b = bid & 7;                  // batch -> XCD pinning for yT[b]
    m0loc = (bid >> 3) * 64;
    Ab = A0 + ((size_t)b * 2048 + m0loc) * APITCH;
    Bb = B0 + (size_t)b * 512 * 2048;
  }

  const int tid = threadIdx.x, lane = tid & 63, w = tid >> 6;
  const int r = lane & 15, hi = lane >> 4;

  // A staging: wave w, instr j cover LDS [w*2048 + j*1024 + lane*16].
  // LDS (row, chunk16 p) must hold A[row][4*(p ^ (row&7)) ...] -> pre-swizzle source.
  const int p16 = lane & 15;
  const int srow0 = w * 8 + (lane >> 4);
  const float* gs0 = Ab + (size_t)srow0 * APITCH + ((p16 ^ (srow0 & 7)) * 4);
  const float* gs1 = Ab + (size_t)(srow0 + 4) * APITCH + ((p16 ^ ((srow0 + 4) & 7)) * 4);
  char* lbase = (char*)&Abuf[0][0] + w * 2048;  // wave-uniform

  const unsigned short* bp[4];
#pragma unroll
  for (int ni = 0; ni < 4; ++ni)
    bp[ni] = Bb + (size_t)(w * 64 + ni * 16 + r) * BPITCH + hi * 8;

  // A-frag LDS byte offsets within a slot: row=mi*16+r, fp32 k = kk*32+hi*8 (+4)
  int aoff[4][2][2];
#pragma unroll
  for (int mi = 0; mi < 4; ++mi)
#pragma unroll
    for (int kk = 0; kk < 2; ++kk) {
      const int row = mi * 16 + r;
      const int c0 = kk * 8 + hi * 2;
#pragma unroll
      for (int h = 0; h < 2; ++h)
        aoff[mi][kk][h] = row * 256 + (((c0 + h) ^ (r & 7)) << 4);
    }

  f32x4 acc[4][4] = {};
  unsigned anz[4] = {0u, 0u, 0u, 0u};
  bf16x8 bc[4][2], bn[4][2];

  // prologue: B(0) first (so vmcnt(2) math holds), then A stages 0..2
#pragma unroll
  for (int ni = 0; ni < 4; ++ni)
#pragma unroll
    for (int kk = 0; kk < 2; ++kk) bc[ni][kk] = gload16(bp[ni] + kk * 32);
  __builtin_amdgcn_sched_barrier(0);
#pragma unroll
  for (int s = 0; s < 3; ++s) {
    gl2lds16(gs0 + s * 64, lbase + s * 16384);
    gl2lds16(gs1 + s * 64, lbase + s * 16384 + 1024);
  }
  __builtin_amdgcn_sched_barrier(0);

#define PIPE_BODY(T, BCC, BCN)                                                    \
  {                                                                               \
    asm volatile("s_waitcnt vmcnt(2)");                                           \
    __builtin_amdgcn_sched_barrier(0);                                            \
    __builtin_amdgcn_s_barrier();                                                 \
    const int tb1 = ((T) + 1 < NT) ? (T) + 1 : NT - 1;                            \
    const int ta3 = ((T) + 3 < NT) ? (T) + 3 : NT - 1;                            \
    const int slot = ((T) + 3) & 3;                                               \
    _Pragma("unroll") for (int ni = 0; ni < 4; ++ni)                              \
        _Pragma("unroll") for (int kk = 0; kk < 2; ++kk)                          \
            BCN[ni][kk] = gload16(bp[ni] + tb1 * 64 + kk * 32);                   \
    __builtin_amdgcn_sched_barrier(0);                                            \
    gl2lds16(gs0 + ta3 * 64, lbase + slot * 16384);                               \
    gl2lds16(gs1 + ta3 * 64, lbase + slot * 16384 + 1024);                        \
    __builtin_amdgcn_sched_barrier(0);                                            \
    const char* sb = (const char*)&Abuf[(T) & 3][0];                              \
    _Pragma("unroll") for (int mi = 0; mi < 4; ++mi)                              \
        _Pragma("unroll") for (int kk = 0; kk < 2; ++kk) {                        \
          f32x4 lo = *(const f32x4*)(sb + aoff[mi][kk][0]);                       \
          f32x4 hh = *(const f32x4*)(sb + aoff[mi][kk][1]);                       \
          if constexpr (IS_Y) {                                                   \
            if (w == 0) {                                                         \
              u32x4 u0 = __builtin_bit_cast(u32x4, lo);                           \
              u32x4 u1 = __builtin_bit_cast(u32x4, hh);                           \
              anz[mi] |= (u0[0] | u0[1] | u0[2] | u0[3] | u1[0] | u1[1] | u1[2] | \
                          u1[3]) & 0x7fffffffu;                                   \
            }                                                                     \
          }                                                                       \
          bf16x8 af = cvt8v(lo, hh);                                              \
          _Pragma("unroll") for (int ni = 0; ni < 4; ++ni)                        \
              acc[mi][ni] = __builtin_amdgcn_mfma_f32_16x16x32_bf16(              \
                  af, BCC[ni][kk], acc[mi][ni], 0, 0, 0);                         \
        }                                                                         \
  }

#pragma unroll 1
  for (int t = 0; t < NT; t += 2) {
    PIPE_BODY(t, bc, bn)
    PIPE_BODY(t + 1, bn, bc)
  }
#undef PIPE_BODY

  asm volatile("s_waitcnt vmcnt(0)");  // drain clamped tail issues before epilogue

  if constexpr (IS_Y) {
    if (w == 0) {
#pragma unroll
      for (int mi = 0; mi < 4; ++mi) {
        unsigned v = anz[mi];
        v |= __shfl_xor(v, 16);
        v |= __shfl_xor(v, 32);
        if (hi == 0) mask[b * 2048 + m0loc + mi * 16 + r] = (v != 0u) ? 1 : 0;
      }
    }
#pragma unroll
    for (int mi = 0; mi < 4; ++mi)
#pragma unroll
      for (int ni = 0; ni < 4; ++ni) {
        const int col = w * 64 + ni * 16 + r;
        ushort4 s;
        s.x = f2bf(acc[mi][ni][0]);
        s.y = f2bf(acc[mi][ni][1]);
        s.z = f2bf(acc[mi][ni][2]);
        s.w = f2bf(acc[mi][ni][3]);
        *(ushort4*)(yT + (((size_t)b * 512 + col) << 11) + m0loc + mi * 16 + hi * 4) = s;
      }
  } else {
    const int* mrow = mask + b * 2048 + m0loc;
#pragma unroll
    for (int mi = 0; mi < 4; ++mi) {
      const int4 mv = *(const int4*)(mrow + mi * 16 + hi * 4);
      const int mvv[4] = {mv.x, mv.y, mv.z, mv.w};
#pragma unroll
      for (int ni = 0; ni < 4; ++ni) {
        const int col = w * 64 + ni * 16 + r;
        float* op = out + ((size_t)(b * 2048 + m0loc + mi * 16 + hi * 4)) * 512 + col;
#pragma unroll
        for (int rr = 0; rr < 4; ++rr) {
          float v = fmaxf(acc[mi][ni][rr], 0.0f);
          if (mvv[rr] == 0) v = 0.0f;
          op[(size_t)rr * 512] = v;
        }
      }
    }
  }
}

// ---------------- launch ----------------------------------------------------------
extern "C" void kernel_launch(void* const* d_in, const int* in_sizes, int n_in,
                              void* d_out, int out_size, void* d_ws, size_t ws_size,
                              hipStream_t stream) {
  const float* x = (const float*)d_in[0];   // [8][2048][512]
  const float* a = (const float*)d_in[1];   // [8][2048][2048]
  const float* wk = (const float*)d_in[2];  // [512][512]
  float* out = (float*)d_out;               // [8][2048][512]

  char* ws = (char*)d_ws;
  unsigned short* wT = (unsigned short*)ws;                 // 512 KB
  unsigned short* yT = (unsigned short*)(ws + (1u << 19));  // 16 MB
  int* mask = (int*)(ws + (1u << 19) + (16u << 20));        // 64 KB

  transpose_cvt<<<dim3(16, 16), dim3(32, 8), 0, stream>>>(wk, wT);
  // y^T = (x @ W)^T, bf16, + exact row mask
  gemm_pipe<512, 512, 8, true><<<256, 512, 0, stream>>>(x, wT, yT, mask, nullptr);
  // out = relu(a @ y) * mask
  gemm_pipe<2048, 2048, 32, false><<<256, 512, 0, stream>>>(a, yT, nullptr, mask, out);
}